// Round 10
// baseline (1465.836 us; speedup 1.0000x reference)
//
#include <hip/hip_runtime.h>

#define EPSV 1e-5f
#define SCOPE_AGENT __HIP_MEMORY_SCOPE_AGENT

__device__ __forceinline__ float fast_rcp(float x) { return __builtin_amdgcn_rcpf(x); }
__device__ __forceinline__ float tanhfast(float x) {
    float e = __expf(2.0f * x);
    return 1.0f - 2.0f * fast_rcp(e + 1.0f);
}
__device__ __forceinline__ float dot4(const float4 w, const float4 v, float a) {
    a = fmaf(w.x, v.x, a);
    a = fmaf(w.y, v.y, a);
    a = fmaf(w.z, v.z, a);
    a = fmaf(w.w, v.w, a);
    return a;
}
#define DPPF(v, ctrl) __int_as_float(__builtin_amdgcn_mov_dpp(__float_as_int(v), (ctrl), 0xF, 0xF, false))

// Pin a float4 into VGPRs: the value becomes asm-defined, so the compiler cannot
// rematerialize it via per-step global reloads (VGPR_Count=92 < 128 weight regs
// proved rec1's weights were being reloaded from L2 inside every LSTM step).
#define KEEP4(v) asm volatile("" : "+v"((v).x), "+v"((v).y), "+v"((v).z), "+v"((v).w))

// Light barrier: LDS-only fence (s_waitcnt lgkmcnt(0) + s_barrier), skipping the
// vmcnt(0) drain __syncthreads() emits. Use ONLY where no global-memory ordering
// is required across the barrier. sched_barrier(0) pins code motion (rule 18).
#define BAR_LDS() do { \
        asm volatile("s_waitcnt lgkmcnt(0)" ::: "memory"); \
        __builtin_amdgcn_s_barrier(); \
        __builtin_amdgcn_sched_barrier(0); \
    } while (0)

typedef unsigned long long ull;

// ---- LDS overlays ----
struct RecS {
    float hbuf[2][80];
    float ring[16][64];
    float xst[16][80];
};
// Edge tap rows: A1[i][36]: slots 0..15 = LEFT  (slot m = a1w(m-3): 0..2 zero, 3..6 computed p=0..3,
//                                                7..12 = a1f[t..t+5], 13..15 zero)
//                           slots 16..31 = RIGHT (rel m = a1w(40+m): 0..5 = a1f[t+36..t+41],
//                                                6..9 computed p=46..49, 10..15 zero)
// A2[i][36]: slots 0..15 LEFT  (slot m = a2w(m-2): 0,1 zero, 2..8 computed q=0..6,
//                               9..12 = a2f[t..t+3], 13..15 zero)
//            slots 16..31 RIGHT (rel m = a2w(39+m): 0..3 = a2f[t+32..t+35],
//                               4..10 computed q=43..49, 11..15 zero)
struct EdgeS {
    float A1[64 * 36];
    float A2[32 * 36];
    float xl[16], xr[16];
    float s1[64], t1[64], s2[32], t2[32], s3[16], t3[16];
    float psumE[288];      // 18 pos x 16 o
    float pi[512];         // 32 dv x 16 o interior a3f
};

// ------- pack: w2 -> w2t2[(i*32+o)*8+k]; w3 -> w3p4/w3p1[(i*16+o)]; zero sync ints -------
__global__ void pack_kernel(const float* __restrict__ w2, const float* __restrict__ w3,
                            float* __restrict__ w2t2, float4* __restrict__ w3p4,
                            float* __restrict__ w3p1, int* __restrict__ sync_ints) {
    int j = blockIdx.x * 256 + threadIdx.x;
    if (j < 16384) {
        int i = j >> 8;
        int o = (j >> 3) & 31;
        int k = j & 7;
        w2t2[j] = (k < 7) ? w2[o * 448 + i * 7 + k] : 0.0f;
    } else if (j < 16896) {
        int e = j - 16384;
        int i = e >> 4, o = e & 15;
        int base = o * 160 + i * 5;
        w3p4[e] = make_float4(w3[base], w3[base + 1], w3[base + 2], w3[base + 3]);
        w3p1[e] = w3[base + 4];
    } else if (j < 16896 + 4096) {
        sync_ints[j - 16896] = 0;
    }
}

// ---------------- full-seq conv1: a1f[(b*2089+v1)*64+i], taps x(v1-49+k) ----------------
__global__ __launch_bounds__(256) void conv1f_kernel(
    const float* __restrict__ x, const float* __restrict__ w1,
    const float* __restrict__ b1, const float* __restrict__ g1,
    const float* __restrict__ be1, const float* __restrict__ m1,
    const float* __restrict__ vv1, float* __restrict__ a1f)
{
    __shared__ float xs[72];
    const int tid = threadIdx.x;
    const int T = blockIdx.x * 64;
    const int b = blockIdx.y;
    if (tid < 72) {
        int gi = T - 49 + tid;
        xs[tid] = (gi >= 0 && gi < 2048) ? x[b * 2048 + gi] : 0.0f;
    }
    const int i = tid & 63, q = tid >> 6;
    float wv[9];
    #pragma unroll
    for (int k = 0; k < 9; ++k) wv[k] = w1[i * 9 + k];
    float sc = g1[i] * rsqrtf(vv1[i] + EPSV);
    float tc = (b1[i] - m1[i]) * sc + be1[i];
    __syncthreads();
    #pragma unroll
    for (int r = 0; r < 16; ++r) {
        int v1 = T + q * 16 + r;
        if (v1 < 2089) {
            float acc = 0.0f;
            #pragma unroll
            for (int k = 0; k < 9; ++k) acc = fmaf(wv[k], xs[q * 16 + r + k], acc);
            a1f[((long)b * 2089 + v1) * 64 + i] = fmaxf(acc * sc + tc, 0.0f);
        }
    }
}

// ---------------- full-seq conv2: a2f[(b*2083+v2)*32+o], taps a1f[v2+k] ----------------
__global__ __launch_bounds__(256) void conv2f_kernel(
    const float* __restrict__ a1f, const float* __restrict__ w2t2,
    const float* __restrict__ b2, const float* __restrict__ g2,
    const float* __restrict__ be2, const float* __restrict__ m2,
    const float* __restrict__ vv2, float* __restrict__ a2f)
{
    __shared__ __align__(16) float As[64 * 104];
    const int tid = threadIdx.x;
    const int T = blockIdx.x * 64;
    const int b = blockIdx.y;
    for (int idx = tid; idx < 1120; idx += 256) {
        int j = idx >> 4, i4 = (idx & 15) * 4;
        int v1 = T + j; if (v1 > 2088) v1 = 2088;
        float4 f = *(const float4*)&a1f[((long)b * 2089 + v1) * 64 + i4];
        int sj = j + ((j >> 3) << 2);
        As[(i4 + 0) * 104 + sj] = f.x;
        As[(i4 + 1) * 104 + sj] = f.y;
        As[(i4 + 2) * 104 + sj] = f.z;
        As[(i4 + 3) * 104 + sj] = f.w;
    }
    const int o = tid >> 3, pg = tid & 7;
    float sc = g2[o] * rsqrtf(vv2[o] + EPSV);
    float tc = (b2[o] - m2[o]) * sc + be2[o];
    __syncthreads();
    float acc[8];
    #pragma unroll
    for (int q = 0; q < 8; ++q) acc[q] = 0.0f;
    for (int i = 0; i < 64; ++i) {
        const float* rowp = &As[i * 104 + 12 * pg];
        float4 A0 = *(const float4*)&rowp[0];
        float4 A1 = *(const float4*)&rowp[4];
        float4 A2 = *(const float4*)&rowp[12];
        float2 A3 = *(const float2*)&rowp[16];
        const float4* wp = (const float4*)&w2t2[(i * 32 + o) * 8];
        float4 Wa = wp[0], Wb = wp[1];
        float av[14] = {A0.x, A0.y, A0.z, A0.w, A1.x, A1.y, A1.z, A1.w,
                        A2.x, A2.y, A2.z, A2.w, A3.x, A3.y};
        float wk[7] = {Wa.x, Wa.y, Wa.z, Wa.w, Wb.x, Wb.y, Wb.z};
        #pragma unroll
        for (int k = 0; k < 7; ++k) {
            #pragma unroll
            for (int q = 0; q < 8; ++q) acc[q] = fmaf(wk[k], av[q + k], acc[q]);
        }
    }
    #pragma unroll
    for (int q = 0; q < 8; ++q) {
        int v2 = T + pg * 8 + q;
        if (v2 < 2083)
            a2f[((long)b * 2083 + v2) * 32 + o] = fmaxf(acc[q] * sc + tc, 0.0f);
    }
}

// ---------------- full-seq conv3: a3f[(b*2080+v3)*16+o], taps a2f[v3+k] ----------------
__global__ __launch_bounds__(256) void conv3f_kernel(
    const float* __restrict__ a2f,
    const float4* __restrict__ w3p4, const float* __restrict__ w3p1,
    const float* __restrict__ b3, const float* __restrict__ g3,
    const float* __restrict__ be3, const float* __restrict__ m3,
    const float* __restrict__ vv3, float* __restrict__ a3f)
{
    __shared__ __align__(16) float A2s[32 * 200];
    const int tid = threadIdx.x;
    const int T = blockIdx.x * 128;
    const int b = blockIdx.y;
    for (int idx = tid; idx < 1056; idx += 256) {
        int j = idx >> 3, i4 = (idx & 7) * 4;
        int v2 = T + j; if (v2 > 2082) v2 = 2082;
        float4 f = *(const float4*)&a2f[((long)b * 2083 + v2) * 32 + i4];
        int sj = j + ((j >> 3) << 2);
        A2s[(i4 + 0) * 200 + sj] = f.x;
        A2s[(i4 + 1) * 200 + sj] = f.y;
        A2s[(i4 + 2) * 200 + sj] = f.z;
        A2s[(i4 + 3) * 200 + sj] = f.w;
    }
    const int o = tid & 15, pg = tid >> 4;
    float sc = g3[o] * rsqrtf(vv3[o] + EPSV);
    float tc = (b3[o] - m3[o]) * sc + be3[o];
    __syncthreads();
    float acc[8];
    #pragma unroll
    for (int q = 0; q < 8; ++q) acc[q] = 0.0f;
    for (int i = 0; i < 32; ++i) {
        const float* rowp = &A2s[i * 200 + 12 * pg];
        float4 R0 = *(const float4*)&rowp[0];
        float4 R1 = *(const float4*)&rowp[4];
        float4 R2 = *(const float4*)&rowp[12];
        float av[12] = {R0.x, R0.y, R0.z, R0.w, R1.x, R1.y, R1.z, R1.w,
                        R2.x, R2.y, R2.z, R2.w};
        float4 wa = w3p4[i * 16 + o];
        float w4 = w3p1[i * 16 + o];
        #pragma unroll
        for (int q = 0; q < 8; ++q) {
            acc[q] = fmaf(wa.x, av[q], acc[q]);
            acc[q] = fmaf(wa.y, av[q + 1], acc[q]);
            acc[q] = fmaf(wa.z, av[q + 2], acc[q]);
            acc[q] = fmaf(wa.w, av[q + 3], acc[q]);
            acc[q] = fmaf(w4,   av[q + 4], acc[q]);
        }
    }
    #pragma unroll
    for (int q = 0; q < 8; ++q) {
        int v3 = T + pg * 8 + q;
        if (v3 < 2079)
            a3f[((long)b * 2080 + v3) * 16 + o] = fmaxf(acc[q] * sc + tc, 0.0f);
        else if (v3 < 2080)
            a3f[((long)b * 2080 + v3) * 16 + o] = 0.0f;
    }
}

// ================= layer-0 recurrence body (weights pinned resident via KEEP4) ====
__device__ __forceinline__ void rec0_body(char* smemraw, int b,
    const float* __restrict__ feats,
    const float* __restrict__ wih, const float* __restrict__ whh,
    const float* __restrict__ bih, const float* __restrict__ bhh,
    float* __restrict__ hout, int* __restrict__ cnt0, int* __restrict__ flag1)
{
    RecS* s = (RecS*)smemraw;
    const int tid = threadIdx.x;
    const int j = tid >> 2, kq = tid & 3;

    const float4* pa = (const float4*)(whh + (0 * 64 + j) * 64 + kq * 16);
    const float4* pb = (const float4*)(whh + (1 * 64 + j) * 64 + kq * 16);
    const float4* pc_ = (const float4*)(whh + (2 * 64 + j) * 64 + kq * 16);
    const float4* pd = (const float4*)(whh + (3 * 64 + j) * 64 + kq * 16);
    float4 A0 = pa[0], A1 = pa[1], A2 = pa[2], A3 = pa[3];
    float4 B0 = pb[0], B1 = pb[1], B2 = pb[2], B3 = pb[3];
    float4 C0 = pc_[0], C1 = pc_[1], C2 = pc_[2], C3 = pc_[3];
    float4 D0 = pd[0], D1 = pd[1], D2 = pd[2], D3 = pd[3];
    float4 xw0 = *(const float4*)(wih + (0 * 64 + j) * 16 + kq * 4);
    float4 xw1 = *(const float4*)(wih + (1 * 64 + j) * 16 + kq * 4);
    float4 xw2 = *(const float4*)(wih + (2 * 64 + j) * 16 + kq * 4);
    float4 xw3 = *(const float4*)(wih + (3 * 64 + j) * 16 + kq * 4);
    KEEP4(A0); KEEP4(A1); KEEP4(A2); KEEP4(A3);
    KEEP4(B0); KEEP4(B1); KEEP4(B2); KEEP4(B3);
    KEEP4(C0); KEEP4(C1); KEEP4(C2); KEEP4(C3);
    KEEP4(D0); KEEP4(D1); KEEP4(D2); KEEP4(D3);
    KEEP4(xw0); KEEP4(xw1); KEEP4(xw2); KEEP4(xw3);
    const float bb0 = bih[j] + bhh[j];
    const float bb1 = bih[64 + j] + bhh[64 + j];
    const float bb2 = bih[128 + j] + bhh[128 + j];
    const float bb3 = bih[192 + j] + bhh[192 + j];

    if (tid < 64) s->hbuf[1][(tid >> 4) * 20 + (tid & 15)] = 0.0f;
    float cst = 0.0f;
    const float* fbase = feats + (long)b * 32768;
    __syncthreads();

#define STEP0(k) { \
        const float4* hp_ = (const float4*)&s->hbuf[((k) + 1) & 1][kq * 20]; \
        float4 h0_ = hp_[0], h1_ = hp_[1], h2_ = hp_[2], h3_ = hp_[3]; \
        float4 xv_ = *(const float4*)&s->xst[(k)][kq * 4]; \
        float p0 = dot4(A3, h3_, dot4(A2, h2_, dot4(A1, h1_, dot4(A0, h0_, dot4(xw0, xv_, 0.f))))); \
        float p1 = dot4(B3, h3_, dot4(B2, h2_, dot4(B1, h1_, dot4(B0, h0_, dot4(xw1, xv_, 0.f))))); \
        float p2 = dot4(C3, h3_, dot4(C2, h2_, dot4(C1, h1_, dot4(C0, h0_, dot4(xw2, xv_, 0.f))))); \
        float p3 = dot4(D3, h3_, dot4(D2, h2_, dot4(D1, h1_, dot4(D0, h0_, dot4(xw3, xv_, 0.f))))); \
        p0 += DPPF(p0, 0xB1); p1 += DPPF(p1, 0xB1); p2 += DPPF(p2, 0xB1); p3 += DPPF(p3, 0xB1); \
        p0 += DPPF(p0, 0x4E); p1 += DPPF(p1, 0x4E); p2 += DPPF(p2, 0x4E); p3 += DPPF(p3, 0x4E); \
        float gi = 1.0f - fast_rcp(__expf(p0 + bb0) + 1.0f); \
        float gf = 1.0f - fast_rcp(__expf(p1 + bb1) + 1.0f); \
        float gg = 1.0f - 2.0f * fast_rcp(__expf(2.0f * (p2 + bb2)) + 1.0f); \
        float go = 1.0f - fast_rcp(__expf(p3 + bb3) + 1.0f); \
        cst = fmaf(gf, cst, gi * gg); \
        float h_ = go * tanhfast(cst); \
        if (kq == 0) { s->hbuf[(k) & 1][(j >> 4) * 20 + (j & 15)] = h_; s->ring[(k)][j] = h_; } \
        BAR_LDS(); \
    }

    for (int c = 0; c < 128; ++c) {
        if (tid == 0) {
            while (__hip_atomic_load(&cnt0[b * 128 + c], __ATOMIC_RELAXED, SCOPE_AGENT) < 16)
                __builtin_amdgcn_s_sleep(2);
        }
        __syncthreads();
        s->xst[tid >> 4][tid & 15] =
            __hip_atomic_load(fbase + c * 256 + tid, __ATOMIC_RELAXED, SCOPE_AGENT);
        BAR_LDS();
        STEP0(0)  STEP0(1)  STEP0(2)  STEP0(3)
        STEP0(4)  STEP0(5)  STEP0(6)  STEP0(7)
        STEP0(8)  STEP0(9)  STEP0(10) STEP0(11)
        STEP0(12) STEP0(13) STEP0(14) STEP0(15)
        {
            ull* dst = (ull*)(hout + ((long)b * 2048 + c * 16) * 64);
            ull v0 = ((const ull*)s->ring)[tid];
            ull v1 = ((const ull*)s->ring)[tid + 256];
            __hip_atomic_store(dst + tid, v0, __ATOMIC_RELAXED, SCOPE_AGENT);
            __hip_atomic_store(dst + tid + 256, v1, __ATOMIC_RELAXED, SCOPE_AGENT);
            __syncthreads();   // full drain: hout stores complete before flag
            if (tid == 0)
                __hip_atomic_store(&flag1[b * 128 + c], 1, __ATOMIC_RELAXED, SCOPE_AGENT);
        }
    }
#undef STEP0
}

// ================= layer-1 recurrence body (weights pinned resident via KEEP4) ========
__device__ __forceinline__ void rec1_body(char* smemraw, int b,
    const float* __restrict__ h1o,
    const float* __restrict__ wih, const float* __restrict__ whh,
    const float* __restrict__ bih, const float* __restrict__ bhh,
    float* __restrict__ hout, int* __restrict__ flag1)
{
    RecS* s = (RecS*)smemraw;
    const int tid = threadIdx.x;
    const int j = tid >> 2, kq = tid & 3;

    const float4* pa = (const float4*)(whh + (0 * 64 + j) * 64 + kq * 16);
    const float4* pb = (const float4*)(whh + (1 * 64 + j) * 64 + kq * 16);
    const float4* pc_ = (const float4*)(whh + (2 * 64 + j) * 64 + kq * 16);
    const float4* pd = (const float4*)(whh + (3 * 64 + j) * 64 + kq * 16);
    float4 A0 = pa[0], A1 = pa[1], A2 = pa[2], A3 = pa[3];
    float4 B0 = pb[0], B1 = pb[1], B2 = pb[2], B3 = pb[3];
    float4 C0 = pc_[0], C1 = pc_[1], C2 = pc_[2], C3 = pc_[3];
    float4 D0 = pd[0], D1 = pd[1], D2 = pd[2], D3 = pd[3];
    const float4* qa = (const float4*)(wih + (0 * 64 + j) * 64 + kq * 16);
    const float4* qb = (const float4*)(wih + (1 * 64 + j) * 64 + kq * 16);
    const float4* qc = (const float4*)(wih + (2 * 64 + j) * 64 + kq * 16);
    const float4* qd = (const float4*)(wih + (3 * 64 + j) * 64 + kq * 16);
    float4 XA0 = qa[0], XA1 = qa[1], XA2 = qa[2], XA3 = qa[3];
    float4 XB0 = qb[0], XB1 = qb[1], XB2 = qb[2], XB3 = qb[3];
    float4 XC0 = qc[0], XC1 = qc[1], XC2 = qc[2], XC3 = qc[3];
    float4 XD0 = qd[0], XD1 = qd[1], XD2 = qd[2], XD3 = qd[3];
    KEEP4(A0); KEEP4(A1); KEEP4(A2); KEEP4(A3);
    KEEP4(B0); KEEP4(B1); KEEP4(B2); KEEP4(B3);
    KEEP4(C0); KEEP4(C1); KEEP4(C2); KEEP4(C3);
    KEEP4(D0); KEEP4(D1); KEEP4(D2); KEEP4(D3);
    KEEP4(XA0); KEEP4(XA1); KEEP4(XA2); KEEP4(XA3);
    KEEP4(XB0); KEEP4(XB1); KEEP4(XB2); KEEP4(XB3);
    KEEP4(XC0); KEEP4(XC1); KEEP4(XC2); KEEP4(XC3);
    KEEP4(XD0); KEEP4(XD1); KEEP4(XD2); KEEP4(XD3);
    const float bb0 = bih[j] + bhh[j];
    const float bb1 = bih[64 + j] + bhh[64 + j];
    const float bb2 = bih[128 + j] + bhh[128 + j];
    const float bb3 = bih[192 + j] + bhh[192 + j];

    if (tid < 64) s->hbuf[1][(tid >> 4) * 20 + (tid & 15)] = 0.0f;
    float cst = 0.0f;
    __syncthreads();

#define STEP1(k) { \
        const float4* hp_ = (const float4*)&s->hbuf[((k) + 1) & 1][kq * 20]; \
        float4 h0_ = hp_[0], h1_ = hp_[1], h2_ = hp_[2], h3_ = hp_[3]; \
        const float4* xp_ = (const float4*)&s->xst[(k)][kq * 20]; \
        float4 x0_ = xp_[0], x1_ = xp_[1], x2_ = xp_[2], x3_ = xp_[3]; \
        float p0 = dot4(A3, h3_, dot4(A2, h2_, dot4(A1, h1_, dot4(A0, h0_, \
                   dot4(XA3, x3_, dot4(XA2, x2_, dot4(XA1, x1_, dot4(XA0, x0_, 0.f)))))))); \
        float p1 = dot4(B3, h3_, dot4(B2, h2_, dot4(B1, h1_, dot4(B0, h0_, \
                   dot4(XB3, x3_, dot4(XB2, x2_, dot4(XB1, x1_, dot4(XB0, x0_, 0.f)))))))); \
        float p2 = dot4(C3, h3_, dot4(C2, h2_, dot4(C1, h1_, dot4(C0, h0_, \
                   dot4(XC3, x3_, dot4(XC2, x2_, dot4(XC1, x1_, dot4(XC0, x0_, 0.f)))))))); \
        float p3 = dot4(D3, h3_, dot4(D2, h2_, dot4(D1, h1_, dot4(D0, h0_, \
                   dot4(XD3, x3_, dot4(XD2, x2_, dot4(XD1, x1_, dot4(XD0, x0_, 0.f)))))))); \
        p0 += DPPF(p0, 0xB1); p1 += DPPF(p1, 0xB1); p2 += DPPF(p2, 0xB1); p3 += DPPF(p3, 0xB1); \
        p0 += DPPF(p0, 0x4E); p1 += DPPF(p1, 0x4E); p2 += DPPF(p2, 0x4E); p3 += DPPF(p3, 0x4E); \
        float gi = 1.0f - fast_rcp(__expf(p0 + bb0) + 1.0f); \
        float gf = 1.0f - fast_rcp(__expf(p1 + bb1) + 1.0f); \
        float gg = 1.0f - 2.0f * fast_rcp(__expf(2.0f * (p2 + bb2)) + 1.0f); \
        float go = 1.0f - fast_rcp(__expf(p3 + bb3) + 1.0f); \
        cst = fmaf(gf, cst, gi * gg); \
        float h_ = go * tanhfast(cst); \
        if (kq == 0) { s->hbuf[(k) & 1][(j >> 4) * 20 + (j & 15)] = h_; s->ring[(k)][j] = h_; } \
        BAR_LDS(); \
    }

    for (int c = 0; c < 128; ++c) {
        if (tid == 0) {
            while (__hip_atomic_load(&flag1[b * 128 + c], __ATOMIC_RELAXED, SCOPE_AGENT) < 1)
                __builtin_amdgcn_s_sleep(2);
        }
        __syncthreads();
        {
            const ull* src = (const ull*)(h1o + ((long)b * 2048 + c * 16) * 64);
            ull v0 = __hip_atomic_load(src + tid, __ATOMIC_RELAXED, SCOPE_AGENT);
            ull v1 = __hip_atomic_load(src + tid + 256, __ATOMIC_RELAXED, SCOPE_AGENT);
            int u0 = tid, u1 = tid + 256;
            int k0 = u0 >> 5, p0i = (u0 & 31) * 2;
            int k1 = u1 >> 5, p1i = (u1 & 31) * 2;
            *(ull*)&s->xst[k0][(p0i >> 4) * 20 + (p0i & 15)] = v0;
            *(ull*)&s->xst[k1][(p1i >> 4) * 20 + (p1i & 15)] = v1;
        }
        BAR_LDS();
        STEP1(0)  STEP1(1)  STEP1(2)  STEP1(3)
        STEP1(4)  STEP1(5)  STEP1(6)  STEP1(7)
        STEP1(8)  STEP1(9)  STEP1(10) STEP1(11)
        STEP1(12) STEP1(13) STEP1(14) STEP1(15)
        {
            float4* dst = (float4*)(hout + ((long)b * 2048 + c * 16) * 64);
            dst[tid] = ((const float4*)s->ring)[tid];
        }
    }
#undef STEP1
}

// ================= edge body v3: minimal recompute; phase-3 indices compile-time =============
// Window<->full-seq identities: a1w(p)=a1f[t+p-4] for p in [4,45]; a2w(q)=a2f[t+q-7] for q in [7,42].
// Recompute only: conv1 p={0..3,46..49}; conv2 q={0..6,43..49}; conv3 P3={0..8,41..49}.
__device__ __forceinline__ void edge_body(char* smemraw, int b, int t,
    const float* __restrict__ x,
    const float* __restrict__ w1,
    const float* __restrict__ b1, const float* __restrict__ g1,
    const float* __restrict__ be1, const float* __restrict__ m1, const float* __restrict__ vv1,
    const float* __restrict__ b2, const float* __restrict__ g2,
    const float* __restrict__ be2, const float* __restrict__ m2, const float* __restrict__ vv2,
    const float* __restrict__ b3, const float* __restrict__ g3,
    const float* __restrict__ be3, const float* __restrict__ m3, const float* __restrict__ vv3,
    const float* __restrict__ w2t2,
    const float4* __restrict__ w3p4, const float* __restrict__ w3p1,
    const float* __restrict__ a1f, const float* __restrict__ a2f,
    const float* __restrict__ a3f,
    float* __restrict__ feats, int* __restrict__ cnt0)
{
    EdgeS* s = (EdgeS*)smemraw;
    const int tid = threadIdx.x;

    // ---- phase 0: zero pads, bn consts, x slices, interior fills, a3f staging ----
    for (int idx = tid; idx < 1088; idx += 256) {
        if (idx < 768) {   // A1 zero slots {0,1,2,13,14,15,26..31}
            int row = idx / 12, z = idx - row * 12;
            int slot = (z < 3) ? z : (z < 6 ? 10 + z : 20 + z);
            s->A1[row * 36 + slot] = 0.0f;
        } else {           // A2 zero slots {0,1,13,14,15,27..31}
            int e = idx - 768;
            int row = e / 10, z = e - row * 10;
            int slot = (z < 2) ? z : (z < 5 ? 11 + z : 22 + z);
            s->A2[row * 36 + slot] = 0.0f;
        }
    }
    if (tid < 128) {       // interior a3f staging (v3 = t .. t+31)
        int dv = tid >> 2, o4 = (tid & 3) * 4;
        *(float4*)&s->pi[dv * 16 + o4] =
            *(const float4*)&a3f[((long)b * 2080 + t + dv) * 16 + o4];
    }
    if (tid < 64) {
        float sc = g1[tid] * rsqrtf(vv1[tid] + EPSV);
        s->s1[tid] = sc;
        s->t1[tid] = (b1[tid] - m1[tid]) * sc + be1[tid];
    } else if (tid < 96) {
        int o = tid - 64;
        float sc = g2[o] * rsqrtf(vv2[o] + EPSV);
        s->s2[o] = sc;
        s->t2[o] = (b2[o] - m2[o]) * sc + be2[o];
    } else if (tid < 112) {
        int o = tid - 96;
        float sc = g3[o] * rsqrtf(vv3[o] + EPSV);
        s->s3[o] = sc;
        s->t3[o] = (b3[o] - m3[o]) * sc + be3[o];
    } else if (tid < 128) {
        int m = tid - 112;           // xl[m] = win[m-4]: 0 for m<4, else x[t-53+m]
        float v = 0.0f;
        if (m >= 4) { int gi = t - 53 + m; if (gi >= 0) v = x[b * 2048 + gi]; }
        s->xl[m] = v;
    } else if (tid < 144) {
        int m = tid - 128;           // xr[m] = win[42+m]: 0 for m>7, else x[t-7+m]
        float v = 0.0f;
        if (m <= 7) { int gi = t - 7 + m; if (gi >= 0) v = x[b * 2048 + gi]; }
        s->xr[m] = v;
    }
    {   // interior fills: one float4 global load per thread, 4 scalar LDS writes
        if (tid < 96) {              // A1 left f: slots 7+d = a1f[t+d], d=0..5
            int d = tid >> 4, i4 = (tid & 15) * 4;
            float4 f = *(const float4*)&a1f[((long)b * 2089 + t + d) * 64 + i4];
            int slot = 7 + d;
            s->A1[(i4 + 0) * 36 + slot] = f.x;
            s->A1[(i4 + 1) * 36 + slot] = f.y;
            s->A1[(i4 + 2) * 36 + slot] = f.z;
            s->A1[(i4 + 3) * 36 + slot] = f.w;
        } else if (tid < 192) {      // A1 right f: slots 16+d = a1f[t+36+d], d=0..5
            int e = tid - 96;
            int d = e >> 4, i4 = (e & 15) * 4;
            float4 f = *(const float4*)&a1f[((long)b * 2089 + t + 36 + d) * 64 + i4];
            int slot = 16 + d;
            s->A1[(i4 + 0) * 36 + slot] = f.x;
            s->A1[(i4 + 1) * 36 + slot] = f.y;
            s->A1[(i4 + 2) * 36 + slot] = f.z;
            s->A1[(i4 + 3) * 36 + slot] = f.w;
        } else if (tid < 224) {      // A2 left f: slots 9+d = a2f[t+d], d=0..3
            int e = tid - 192;
            int d = e >> 3, i4 = (e & 7) * 4;
            float4 f = *(const float4*)&a2f[((long)b * 2083 + t + d) * 32 + i4];
            int slot = 9 + d;
            s->A2[(i4 + 0) * 36 + slot] = f.x;
            s->A2[(i4 + 1) * 36 + slot] = f.y;
            s->A2[(i4 + 2) * 36 + slot] = f.z;
            s->A2[(i4 + 3) * 36 + slot] = f.w;
        } else {                     // A2 right f: slots 16+d = a2f[t+32+d], d=0..3
            int e = tid - 224;
            int d = e >> 3, i4 = (e & 7) * 4;
            float4 f = *(const float4*)&a2f[((long)b * 2083 + t + 32 + d) * 32 + i4];
            int slot = 16 + d;
            s->A2[(i4 + 0) * 36 + slot] = f.x;
            s->A2[(i4 + 1) * 36 + slot] = f.y;
            s->A2[(i4 + 2) * 36 + slot] = f.z;
            s->A2[(i4 + 3) * 36 + slot] = f.w;
        }
    }
    __syncthreads();

    {   // ---- phase 1: conv1 edges, 8 positions: left p=g -> slot 3+g, right p=46+g -> slot 22+g
        const int o = tid >> 2, g = tid & 3;
        float wv[9];
        #pragma unroll
        for (int k = 0; k < 9; ++k) wv[k] = w1[o * 9 + k];
        float accL = 0.0f, accR = 0.0f;
        #pragma unroll
        for (int k = 0; k < 9; ++k) {
            accL = fmaf(wv[k], s->xl[g + k], accL);
            accR = fmaf(wv[k], s->xr[g + k], accR);
        }
        float sc = s->s1[o], tc = s->t1[o];
        s->A1[o * 36 + 3 + g]  = fmaxf(accL * sc + tc, 0.0f);
        s->A1[o * 36 + 22 + g] = fmaxf(accR * sc + tc, 0.0f);
    }
    __syncthreads();

    {   // ---- phase 2: conv2 edges, 7 q per side; 4-way i-split + DPP reduce
        const int o = tid >> 3, side = (tid >> 2) & 1, isub = tid & 3;
        const int sbase = side * 16;
        float acc[7];
        #pragma unroll
        for (int q = 0; q < 7; ++q) acc[q] = 0.0f;
        #pragma unroll 2
        for (int ii = 0; ii < 16; ++ii) {
            int i = 4 * ii + isub;
            const float* rp = &s->A1[i * 36 + sbase];
            float4 R0 = *(const float4*)&rp[0];
            float4 R1 = *(const float4*)&rp[4];
            float4 R2 = *(const float4*)&rp[8];
            float r12 = rp[12];
            float av[13] = {R0.x, R0.y, R0.z, R0.w, R1.x, R1.y, R1.z, R1.w,
                            R2.x, R2.y, R2.z, R2.w, r12};
            const float4* wp = (const float4*)&w2t2[(i * 32 + o) * 8];
            float4 Wa = wp[0], Wb = wp[1];
            float wk[7] = {Wa.x, Wa.y, Wa.z, Wa.w, Wb.x, Wb.y, Wb.z};
            #pragma unroll
            for (int k = 0; k < 7; ++k) {
                #pragma unroll
                for (int q = 0; q < 7; ++q) acc[q] = fmaf(wk[k], av[q + k], acc[q]);
            }
        }
        #pragma unroll
        for (int q = 0; q < 7; ++q) {
            acc[q] += DPPF(acc[q], 0xB1);
            acc[q] += DPPF(acc[q], 0x4E);
        }
        if (isub == 0) {
            float sc = s->s2[o], tc = s->t2[o];
            #pragma unroll
            for (int q = 0; q < 7; ++q) {
                float r = fmaxf(acc[q] * sc + tc, 0.0f);
                s->A2[o * 36 + (side ? 20 + q : 2 + q)] = r;
            }
        }
    }
    __syncthreads();

    {   // ---- phase 3: conv3 edges; wave-uniform pg/side branches, ALL tap indices compile-time
        const int o = (tid >> 2) & 15, isub = tid & 3;
        const int side = (tid >> 6) & 1, pg = tid >> 7;   // wave-uniform (64-lane granularity)
        float acc[5];
        #pragma unroll
        for (int n = 0; n < 5; ++n) acc[n] = 0.0f;
        if (pg == 0) {          // positions P=0..4, taps 0..8
            #pragma unroll 2
            for (int ii = 0; ii < 8; ++ii) {
                int i = 4 * ii + isub;
                const float* rp = &s->A2[i * 36 + side * 16];
                float4 R0 = *(const float4*)&rp[0];
                float4 R1 = *(const float4*)&rp[4];
                float t8 = rp[8];
                float av[9] = {R0.x, R0.y, R0.z, R0.w, R1.x, R1.y, R1.z, R1.w, t8};
                float4 wa = w3p4[i * 16 + o];
                float w4 = w3p1[i * 16 + o];
                #pragma unroll
                for (int n = 0; n < 5; ++n) {
                    acc[n] = fmaf(wa.x, av[n], acc[n]);
                    acc[n] = fmaf(wa.y, av[n + 1], acc[n]);
                    acc[n] = fmaf(wa.z, av[n + 2], acc[n]);
                    acc[n] = fmaf(wa.w, av[n + 3], acc[n]);
                    acc[n] = fmaf(w4,   av[n + 4], acc[n]);
                }
            }
        } else {                // positions P=5..8, taps 5..12
            #pragma unroll 2
            for (int ii = 0; ii < 8; ++ii) {
                int i = 4 * ii + isub;
                const float* rp = &s->A2[i * 36 + side * 16];
                float4 R1 = *(const float4*)&rp[4];
                float4 R2 = *(const float4*)&rp[8];
                float t12 = rp[12];
                float av[8] = {R1.y, R1.z, R1.w, R2.x, R2.y, R2.z, R2.w, t12}; // taps 5..12
                float4 wa = w3p4[i * 16 + o];
                float w4 = w3p1[i * 16 + o];
                #pragma unroll
                for (int n = 0; n < 4; ++n) {
                    acc[n] = fmaf(wa.x, av[n], acc[n]);
                    acc[n] = fmaf(wa.y, av[n + 1], acc[n]);
                    acc[n] = fmaf(wa.z, av[n + 2], acc[n]);
                    acc[n] = fmaf(wa.w, av[n + 3], acc[n]);
                    acc[n] = fmaf(w4,   av[n + 4], acc[n]);
                }
            }
        }
        #pragma unroll
        for (int n = 0; n < 5; ++n) {
            acc[n] += DPPF(acc[n], 0xB1);
            acc[n] += DPPF(acc[n], 0x4E);
        }
        if (isub == 0) {
            float sc = s->s3[o], tc = s->t3[o];
            if (pg == 0) {
                #pragma unroll
                for (int n = 0; n < 5; ++n)
                    s->psumE[(side * 9 + n) * 16 + o] = fmaxf(acc[n] * sc + tc, 0.0f);
            } else {
                #pragma unroll
                for (int n = 0; n < 4; ++n)
                    s->psumE[(side * 9 + 5 + n) * 16 + o] = fmaxf(acc[n] * sc + tc, 0.0f);
            }
        }
    }
    __syncthreads();

    if (tid < 16) {
        float e = 0.0f;
        #pragma unroll
        for (int P3 = 0; P3 < 18; ++P3) e += s->psumE[P3 * 16 + tid];
        float ii = 0.0f;
        #pragma unroll
        for (int dv = 0; dv < 32; ++dv) ii += s->pi[dv * 16 + tid];
        __hip_atomic_store(&feats[((long)b * 2048 + t) * 16 + tid], (e + ii) * (1.0f / 50.0f),
                           __ATOMIC_RELAXED, SCOPE_AGENT);
    }
    __syncthreads();   // drains vmcnt(0): feats stores complete before counter bump
    if (tid == 0)
        __hip_atomic_fetch_add(&cnt0[b * 128 + (t >> 4)], 1, __ATOMIC_RELAXED, SCOPE_AGENT);
}

// ================= fused: blocks 0-15 lstm0, 16-31 lstm1, 32+ edge (t-major) =================
__global__ __launch_bounds__(256, 2) void fused_kernel(
    const float* __restrict__ x,
    const float* __restrict__ w1, const float* __restrict__ b1,
    const float* __restrict__ g1, const float* __restrict__ be1,
    const float* __restrict__ m1, const float* __restrict__ vv1,
    const float* __restrict__ b2,
    const float* __restrict__ g2, const float* __restrict__ be2,
    const float* __restrict__ m2, const float* __restrict__ vv2,
    const float* __restrict__ b3,
    const float* __restrict__ g3, const float* __restrict__ be3,
    const float* __restrict__ m3, const float* __restrict__ vv3,
    const float* __restrict__ w2t2,
    const float4* __restrict__ w3p4, const float* __restrict__ w3p1,
    const float* __restrict__ a1f, const float* __restrict__ a2f,
    const float* __restrict__ a3f,
    const float* __restrict__ wih0, const float* __restrict__ whh0,
    const float* __restrict__ bih0, const float* __restrict__ bhh0,
    const float* __restrict__ wih1, const float* __restrict__ whh1,
    const float* __restrict__ bih1, const float* __restrict__ bhh1,
    float* __restrict__ feats, float* __restrict__ h1o, float* __restrict__ h2o,
    int* __restrict__ cnt0, int* __restrict__ flag1)
{
    __shared__ __align__(16) char smem[sizeof(EdgeS) > sizeof(RecS) ? sizeof(EdgeS) : sizeof(RecS)];

    if (blockIdx.x < 16) { rec0_body(smem, blockIdx.x, feats, wih0, whh0, bih0, bhh0, h1o, cnt0, flag1); return; }
    if (blockIdx.x < 32) { rec1_body(smem, blockIdx.x - 16, h1o, wih1, whh1, bih1, bhh1, h2o, flag1); return; }

    int w = blockIdx.x - 32;
    int b = w & 15;          // t-major: early t for all batches first
    int t = w >> 4;
    edge_body(smem, b, t, x, w1, b1, g1, be1, m1, vv1, b2, g2, be2, m2, vv2,
              b3, g3, be3, m3, vv3, w2t2, w3p4, w3p1, a1f, a2f, a3f, feats, cnt0);
}

// ---------------- FC head ----------------
__global__ __launch_bounds__(256) void fc_kernel(
    const float* __restrict__ h2o,
    const float* __restrict__ fc1w, const float* __restrict__ fc1b,
    const float* __restrict__ fc2w, const float* __restrict__ fc2b,
    float* __restrict__ out)
{
    int r = blockIdx.x * 256 + threadIdx.x;
    float h[64];
    const float4* hp = (const float4*)(h2o + (long)r * 64);
    #pragma unroll
    for (int i = 0; i < 16; ++i) {
        float4 v = hp[i];
        h[4 * i] = v.x; h[4 * i + 1] = v.y; h[4 * i + 2] = v.z; h[4 * i + 3] = v.w;
    }
    float l0 = fc2b[0], l1 = fc2b[1];
    #pragma unroll 4
    for (int j = 0; j < 32; ++j) {
        float z = fc1b[j];
        #pragma unroll
        for (int k = 0; k < 64; ++k) z = fmaf(h[k], fc1w[j * 64 + k], z);
        z = fmaxf(z, 0.0f);
        l0 = fmaf(z, fc2w[j], l0);
        l1 = fmaf(z, fc2w[32 + j], l1);
    }
    out[r * 2] = l0;
    out[r * 2 + 1] = l1;
}

extern "C" void kernel_launch(void* const* d_in, const int* in_sizes, int n_in,
                              void* d_out, int out_size, void* d_ws, size_t ws_size,
                              hipStream_t stream) {
    const float* x    = (const float*)d_in[0];
    const float* w1   = (const float*)d_in[1];
    const float* b1   = (const float*)d_in[2];
    const float* g1   = (const float*)d_in[3];
    const float* be1  = (const float*)d_in[4];
    const float* m1   = (const float*)d_in[5];
    const float* v1   = (const float*)d_in[6];
    const float* w2   = (const float*)d_in[7];
    const float* b2   = (const float*)d_in[8];
    const float* g2   = (const float*)d_in[9];
    const float* be2  = (const float*)d_in[10];
    const float* m2   = (const float*)d_in[11];
    const float* v2   = (const float*)d_in[12];
    const float* w3   = (const float*)d_in[13];
    const float* b3   = (const float*)d_in[14];
    const float* g3   = (const float*)d_in[15];
    const float* be3  = (const float*)d_in[16];
    const float* m3   = (const float*)d_in[17];
    const float* v3   = (const float*)d_in[18];
    const float* wih0 = (const float*)d_in[19];
    const float* whh0 = (const float*)d_in[20];
    const float* bih0 = (const float*)d_in[21];
    const float* bhh0 = (const float*)d_in[22];
    const float* wih1 = (const float*)d_in[23];
    const float* whh1 = (const float*)d_in[24];
    const float* bih1 = (const float*)d_in[25];
    const float* bhh1 = (const float*)d_in[26];
    const float* fc1w = (const float*)d_in[27];
    const float* fc1b = (const float*)d_in[28];
    const float* fc2w = (const float*)d_in[29];
    const float* fc2b = (const float*)d_in[30];
    float* out = (float*)d_out;

    float* ws    = (float*)d_ws;
    float* feats = ws;                            // 524288
    float* h2o   = feats + 32768 * 16;            // 2097152
    float* w2t2  = h2o + 32768 * 64;              // 16384
    float* w3p4f = w2t2 + 16384;                  // 2048
    float* w3p1  = w3p4f + 2048;                  // 512
    float* h1o   = w3p1 + 512;                    // 2097152
    float* a1f   = h1o + 32768 * 64;              // 16*2089*64 = 2139136
    float* a2f   = a1f + 16 * 2089 * 64;          // 16*2083*32 = 1066496
    float* a3f   = a2f + 16 * 2083 * 32;          // 16*2080*16 = 532480
    int*   cnt0  = (int*)(a3f + 16 * 2080 * 16);  // 2048
    int*   flag1 = cnt0 + 2048;                   // 2048

    hipLaunchKernelGGL(pack_kernel, dim3(82), dim3(256), 0, stream,
                       w2, w3, w2t2, (float4*)w3p4f, w3p1, cnt0);
    hipLaunchKernelGGL(conv1f_kernel, dim3(33, 16), dim3(256), 0, stream,
                       x, w1, b1, g1, be1, m1, v1, a1f);
    hipLaunchKernelGGL(conv2f_kernel, dim3(33, 16), dim3(256), 0, stream,
                       a1f, w2t2, b2, g2, be2, m2, v2, a2f);
    hipLaunchKernelGGL(conv3f_kernel, dim3(17, 16), dim3(256), 0, stream,
                       a2f, (const float4*)w3p4f, w3p1, b3, g3, be3, m3, v3, a3f);
    hipLaunchKernelGGL(fused_kernel, dim3(32 + 32768), dim3(256), 0, stream,
                       x, w1, b1, g1, be1, m1, v1, b2, g2, be2, m2, v2,
                       b3, g3, be3, m3, v3, w2t2, (const float4*)w3p4f, w3p1,
                       a1f, a2f, a3f,
                       wih0, whh0, bih0, bhh0, wih1, whh1, bih1, bhh1,
                       feats, h1o, h2o, cnt0, flag1);
    hipLaunchKernelGGL(fc_kernel, dim3(128), dim3(256), 0, stream,
                       h2o, fc1w, fc1b, fc2w, fc2b, out);
}

// Round 11
// 1169.994 us; speedup vs baseline: 1.2529x; 1.2529x over previous
//
#include <hip/hip_runtime.h>

#define EPSV 1e-5f
#define SCOPE_AGENT __HIP_MEMORY_SCOPE_AGENT

__device__ __forceinline__ float fast_rcp(float x) { return __builtin_amdgcn_rcpf(x); }
__device__ __forceinline__ float tanhfast(float x) {
    float e = __expf(2.0f * x);
    return 1.0f - 2.0f * fast_rcp(e + 1.0f);
}
__device__ __forceinline__ float dot4(const float4 w, const float4 v, float a) {
    a = fmaf(w.x, v.x, a);
    a = fmaf(w.y, v.y, a);
    a = fmaf(w.z, v.z, a);
    a = fmaf(w.w, v.w, a);
    return a;
}
#define DPPF(v, ctrl) __int_as_float(__builtin_amdgcn_mov_dpp(__float_as_int(v), (ctrl), 0xF, 0xF, false))

// Light barrier: LDS-only fence (s_waitcnt lgkmcnt(0) + s_barrier), skipping the
// vmcnt(0) drain __syncthreads() emits. Use ONLY where no global-memory ordering
// is required across the barrier. sched_barrier(0) pins code motion (rule 18).
#define BAR_LDS() do { \
        asm volatile("s_waitcnt lgkmcnt(0)" ::: "memory"); \
        __builtin_amdgcn_s_barrier(); \
        __builtin_amdgcn_sched_barrier(0); \
    } while (0)

typedef unsigned long long ull;

// ---- LDS overlays ----
struct RecS {
    float hbuf[2][80];
    float ring[16][64];
    float xst[16][80];
};
// Edge tap rows: A1[i][36]: slots 0..15 = LEFT  (slot m = a1w(m-3): 0..2 zero, 3..6 computed p=0..3,
//                                                7..12 = a1f[t..t+5], 13..15 zero)
//                           slots 16..31 = RIGHT (rel m = a1w(40+m): 0..5 = a1f[t+36..t+41],
//                                                6..9 computed p=46..49, 10..15 zero)
// A2[i][36]: slots 0..15 LEFT  (slot m = a2w(m-2): 0,1 zero, 2..8 computed q=0..6,
//                               9..12 = a2f[t..t+3], 13..15 zero)
//            slots 16..31 RIGHT (rel m = a2w(39+m): 0..3 = a2f[t+32..t+35],
//                               4..10 computed q=43..49, 11..15 zero)
struct EdgeS {
    float A1[64 * 36];
    float A2[32 * 36];
    float xl[16], xr[16];
    float s1[64], t1[64], s2[32], t2[32], s3[16], t3[16];
    float psumE[288];      // 18 pos x 16 o
    float pi[512];         // 32 dv x 16 o interior a3f
};

// ------- pack: w2 -> w2t2[(i*32+o)*8+k]; w3 -> w3p4/w3p1[(i*16+o)]; zero sync ints -------
__global__ void pack_kernel(const float* __restrict__ w2, const float* __restrict__ w3,
                            float* __restrict__ w2t2, float4* __restrict__ w3p4,
                            float* __restrict__ w3p1, int* __restrict__ sync_ints) {
    int j = blockIdx.x * 256 + threadIdx.x;
    if (j < 16384) {
        int i = j >> 8;
        int o = (j >> 3) & 31;
        int k = j & 7;
        w2t2[j] = (k < 7) ? w2[o * 448 + i * 7 + k] : 0.0f;
    } else if (j < 16896) {
        int e = j - 16384;
        int i = e >> 4, o = e & 15;
        int base = o * 160 + i * 5;
        w3p4[e] = make_float4(w3[base], w3[base + 1], w3[base + 2], w3[base + 3]);
        w3p1[e] = w3[base + 4];
    } else if (j < 16896 + 4096) {
        sync_ints[j - 16896] = 0;
    }
}

// ---------------- full-seq conv1: a1f[(b*2089+v1)*64+i], taps x(v1-49+k) ----------------
__global__ __launch_bounds__(256) void conv1f_kernel(
    const float* __restrict__ x, const float* __restrict__ w1,
    const float* __restrict__ b1, const float* __restrict__ g1,
    const float* __restrict__ be1, const float* __restrict__ m1,
    const float* __restrict__ vv1, float* __restrict__ a1f)
{
    __shared__ float xs[72];
    const int tid = threadIdx.x;
    const int T = blockIdx.x * 64;
    const int b = blockIdx.y;
    if (tid < 72) {
        int gi = T - 49 + tid;
        xs[tid] = (gi >= 0 && gi < 2048) ? x[b * 2048 + gi] : 0.0f;
    }
    const int i = tid & 63, q = tid >> 6;
    float wv[9];
    #pragma unroll
    for (int k = 0; k < 9; ++k) wv[k] = w1[i * 9 + k];
    float sc = g1[i] * rsqrtf(vv1[i] + EPSV);
    float tc = (b1[i] - m1[i]) * sc + be1[i];
    __syncthreads();
    #pragma unroll
    for (int r = 0; r < 16; ++r) {
        int v1 = T + q * 16 + r;
        if (v1 < 2089) {
            float acc = 0.0f;
            #pragma unroll
            for (int k = 0; k < 9; ++k) acc = fmaf(wv[k], xs[q * 16 + r + k], acc);
            a1f[((long)b * 2089 + v1) * 64 + i] = fmaxf(acc * sc + tc, 0.0f);
        }
    }
}

// ---------------- full-seq conv2: a2f[(b*2083+v2)*32+o], taps a1f[v2+k] ----------------
__global__ __launch_bounds__(256) void conv2f_kernel(
    const float* __restrict__ a1f, const float* __restrict__ w2t2,
    const float* __restrict__ b2, const float* __restrict__ g2,
    const float* __restrict__ be2, const float* __restrict__ m2,
    const float* __restrict__ vv2, float* __restrict__ a2f)
{
    __shared__ __align__(16) float As[64 * 104];
    const int tid = threadIdx.x;
    const int T = blockIdx.x * 64;
    const int b = blockIdx.y;
    for (int idx = tid; idx < 1120; idx += 256) {
        int j = idx >> 4, i4 = (idx & 15) * 4;
        int v1 = T + j; if (v1 > 2088) v1 = 2088;
        float4 f = *(const float4*)&a1f[((long)b * 2089 + v1) * 64 + i4];
        int sj = j + ((j >> 3) << 2);
        As[(i4 + 0) * 104 + sj] = f.x;
        As[(i4 + 1) * 104 + sj] = f.y;
        As[(i4 + 2) * 104 + sj] = f.z;
        As[(i4 + 3) * 104 + sj] = f.w;
    }
    const int o = tid >> 3, pg = tid & 7;
    float sc = g2[o] * rsqrtf(vv2[o] + EPSV);
    float tc = (b2[o] - m2[o]) * sc + be2[o];
    __syncthreads();
    float acc[8];
    #pragma unroll
    for (int q = 0; q < 8; ++q) acc[q] = 0.0f;
    for (int i = 0; i < 64; ++i) {
        const float* rowp = &As[i * 104 + 12 * pg];
        float4 A0 = *(const float4*)&rowp[0];
        float4 A1 = *(const float4*)&rowp[4];
        float4 A2 = *(const float4*)&rowp[12];
        float2 A3 = *(const float2*)&rowp[16];
        const float4* wp = (const float4*)&w2t2[(i * 32 + o) * 8];
        float4 Wa = wp[0], Wb = wp[1];
        float av[14] = {A0.x, A0.y, A0.z, A0.w, A1.x, A1.y, A1.z, A1.w,
                        A2.x, A2.y, A2.z, A2.w, A3.x, A3.y};
        float wk[7] = {Wa.x, Wa.y, Wa.z, Wa.w, Wb.x, Wb.y, Wb.z};
        #pragma unroll
        for (int k = 0; k < 7; ++k) {
            #pragma unroll
            for (int q = 0; q < 8; ++q) acc[q] = fmaf(wk[k], av[q + k], acc[q]);
        }
    }
    #pragma unroll
    for (int q = 0; q < 8; ++q) {
        int v2 = T + pg * 8 + q;
        if (v2 < 2083)
            a2f[((long)b * 2083 + v2) * 32 + o] = fmaxf(acc[q] * sc + tc, 0.0f);
    }
}

// ---------------- full-seq conv3: a3f[(b*2080+v3)*16+o], taps a2f[v3+k] ----------------
__global__ __launch_bounds__(256) void conv3f_kernel(
    const float* __restrict__ a2f,
    const float4* __restrict__ w3p4, const float* __restrict__ w3p1,
    const float* __restrict__ b3, const float* __restrict__ g3,
    const float* __restrict__ be3, const float* __restrict__ m3,
    const float* __restrict__ vv3, float* __restrict__ a3f)
{
    __shared__ __align__(16) float A2s[32 * 200];
    const int tid = threadIdx.x;
    const int T = blockIdx.x * 128;
    const int b = blockIdx.y;
    for (int idx = tid; idx < 1056; idx += 256) {
        int j = idx >> 3, i4 = (idx & 7) * 4;
        int v2 = T + j; if (v2 > 2082) v2 = 2082;
        float4 f = *(const float4*)&a2f[((long)b * 2083 + v2) * 32 + i4];
        int sj = j + ((j >> 3) << 2);
        A2s[(i4 + 0) * 200 + sj] = f.x;
        A2s[(i4 + 1) * 200 + sj] = f.y;
        A2s[(i4 + 2) * 200 + sj] = f.z;
        A2s[(i4 + 3) * 200 + sj] = f.w;
    }
    const int o = tid & 15, pg = tid >> 4;
    float sc = g3[o] * rsqrtf(vv3[o] + EPSV);
    float tc = (b3[o] - m3[o]) * sc + be3[o];
    __syncthreads();
    float acc[8];
    #pragma unroll
    for (int q = 0; q < 8; ++q) acc[q] = 0.0f;
    for (int i = 0; i < 32; ++i) {
        const float* rowp = &A2s[i * 200 + 12 * pg];
        float4 R0 = *(const float4*)&rowp[0];
        float4 R1 = *(const float4*)&rowp[4];
        float4 R2 = *(const float4*)&rowp[12];
        float av[12] = {R0.x, R0.y, R0.z, R0.w, R1.x, R1.y, R1.z, R1.w,
                        R2.x, R2.y, R2.z, R2.w};
        float4 wa = w3p4[i * 16 + o];
        float w4 = w3p1[i * 16 + o];
        #pragma unroll
        for (int q = 0; q < 8; ++q) {
            acc[q] = fmaf(wa.x, av[q], acc[q]);
            acc[q] = fmaf(wa.y, av[q + 1], acc[q]);
            acc[q] = fmaf(wa.z, av[q + 2], acc[q]);
            acc[q] = fmaf(wa.w, av[q + 3], acc[q]);
            acc[q] = fmaf(w4,   av[q + 4], acc[q]);
        }
    }
    #pragma unroll
    for (int q = 0; q < 8; ++q) {
        int v3 = T + pg * 8 + q;
        if (v3 < 2079)
            a3f[((long)b * 2080 + v3) * 16 + o] = fmaxf(acc[q] * sc + tc, 0.0f);
        else if (v3 < 2080)
            a3f[((long)b * 2080 + v3) * 16 + o] = 0.0f;
    }
}

// ================= layer-0 recurrence body (R2 structure; per-step barriers are LDS-only) ====
__device__ __forceinline__ void rec0_body(char* smemraw, int b,
    const float* __restrict__ feats,
    const float* __restrict__ wih, const float* __restrict__ whh,
    const float* __restrict__ bih, const float* __restrict__ bhh,
    float* __restrict__ hout, int* __restrict__ cnt0, int* __restrict__ flag1)
{
    RecS* s = (RecS*)smemraw;
    const int tid = threadIdx.x;
    const int j = tid >> 2, kq = tid & 3;

    const float4* pa = (const float4*)(whh + (0 * 64 + j) * 64 + kq * 16);
    const float4* pb = (const float4*)(whh + (1 * 64 + j) * 64 + kq * 16);
    const float4* pc_ = (const float4*)(whh + (2 * 64 + j) * 64 + kq * 16);
    const float4* pd = (const float4*)(whh + (3 * 64 + j) * 64 + kq * 16);
    float4 A0 = pa[0], A1 = pa[1], A2 = pa[2], A3 = pa[3];
    float4 B0 = pb[0], B1 = pb[1], B2 = pb[2], B3 = pb[3];
    float4 C0 = pc_[0], C1 = pc_[1], C2 = pc_[2], C3 = pc_[3];
    float4 D0 = pd[0], D1 = pd[1], D2 = pd[2], D3 = pd[3];
    float4 xw0 = *(const float4*)(wih + (0 * 64 + j) * 16 + kq * 4);
    float4 xw1 = *(const float4*)(wih + (1 * 64 + j) * 16 + kq * 4);
    float4 xw2 = *(const float4*)(wih + (2 * 64 + j) * 16 + kq * 4);
    float4 xw3 = *(const float4*)(wih + (3 * 64 + j) * 16 + kq * 4);
    const float bb0 = bih[j] + bhh[j];
    const float bb1 = bih[64 + j] + bhh[64 + j];
    const float bb2 = bih[128 + j] + bhh[128 + j];
    const float bb3 = bih[192 + j] + bhh[192 + j];

    if (tid < 64) s->hbuf[1][(tid >> 4) * 20 + (tid & 15)] = 0.0f;
    float cst = 0.0f;
    const float* fbase = feats + (long)b * 32768;
    __syncthreads();

#define STEP0(k) { \
        const float4* hp_ = (const float4*)&s->hbuf[((k) + 1) & 1][kq * 20]; \
        float4 h0_ = hp_[0], h1_ = hp_[1], h2_ = hp_[2], h3_ = hp_[3]; \
        float4 xv_ = *(const float4*)&s->xst[(k)][kq * 4]; \
        float p0 = dot4(A3, h3_, dot4(A2, h2_, dot4(A1, h1_, dot4(A0, h0_, dot4(xw0, xv_, 0.f))))); \
        float p1 = dot4(B3, h3_, dot4(B2, h2_, dot4(B1, h1_, dot4(B0, h0_, dot4(xw1, xv_, 0.f))))); \
        float p2 = dot4(C3, h3_, dot4(C2, h2_, dot4(C1, h1_, dot4(C0, h0_, dot4(xw2, xv_, 0.f))))); \
        float p3 = dot4(D3, h3_, dot4(D2, h2_, dot4(D1, h1_, dot4(D0, h0_, dot4(xw3, xv_, 0.f))))); \
        p0 += DPPF(p0, 0xB1); p1 += DPPF(p1, 0xB1); p2 += DPPF(p2, 0xB1); p3 += DPPF(p3, 0xB1); \
        p0 += DPPF(p0, 0x4E); p1 += DPPF(p1, 0x4E); p2 += DPPF(p2, 0x4E); p3 += DPPF(p3, 0x4E); \
        float gi = 1.0f - fast_rcp(__expf(p0 + bb0) + 1.0f); \
        float gf = 1.0f - fast_rcp(__expf(p1 + bb1) + 1.0f); \
        float gg = 1.0f - 2.0f * fast_rcp(__expf(2.0f * (p2 + bb2)) + 1.0f); \
        float go = 1.0f - fast_rcp(__expf(p3 + bb3) + 1.0f); \
        cst = fmaf(gf, cst, gi * gg); \
        float h_ = go * tanhfast(cst); \
        if (kq == 0) { s->hbuf[(k) & 1][(j >> 4) * 20 + (j & 15)] = h_; s->ring[(k)][j] = h_; } \
        BAR_LDS(); \
    }

    for (int c = 0; c < 128; ++c) {
        if (tid == 0) {
            while (__hip_atomic_load(&cnt0[b * 128 + c], __ATOMIC_RELAXED, SCOPE_AGENT) < 16)
                __builtin_amdgcn_s_sleep(2);
        }
        __syncthreads();
        s->xst[tid >> 4][tid & 15] =
            __hip_atomic_load(fbase + c * 256 + tid, __ATOMIC_RELAXED, SCOPE_AGENT);
        BAR_LDS();
        STEP0(0)  STEP0(1)  STEP0(2)  STEP0(3)
        STEP0(4)  STEP0(5)  STEP0(6)  STEP0(7)
        STEP0(8)  STEP0(9)  STEP0(10) STEP0(11)
        STEP0(12) STEP0(13) STEP0(14) STEP0(15)
        {
            ull* dst = (ull*)(hout + ((long)b * 2048 + c * 16) * 64);
            ull v0 = ((const ull*)s->ring)[tid];
            ull v1 = ((const ull*)s->ring)[tid + 256];
            __hip_atomic_store(dst + tid, v0, __ATOMIC_RELAXED, SCOPE_AGENT);
            __hip_atomic_store(dst + tid + 256, v1, __ATOMIC_RELAXED, SCOPE_AGENT);
            __syncthreads();   // full drain: hout stores complete before flag
            if (tid == 0)
                __hip_atomic_store(&flag1[b * 128 + c], 1, __ATOMIC_RELAXED, SCOPE_AGENT);
        }
    }
#undef STEP0
}

// ================= layer-1 recurrence body (R2 structure; LDS-only per-step barriers) ========
__device__ __forceinline__ void rec1_body(char* smemraw, int b,
    const float* __restrict__ h1o,
    const float* __restrict__ wih, const float* __restrict__ whh,
    const float* __restrict__ bih, const float* __restrict__ bhh,
    float* __restrict__ hout, int* __restrict__ flag1)
{
    RecS* s = (RecS*)smemraw;
    const int tid = threadIdx.x;
    const int j = tid >> 2, kq = tid & 3;

    const float4* pa = (const float4*)(whh + (0 * 64 + j) * 64 + kq * 16);
    const float4* pb = (const float4*)(whh + (1 * 64 + j) * 64 + kq * 16);
    const float4* pc_ = (const float4*)(whh + (2 * 64 + j) * 64 + kq * 16);
    const float4* pd = (const float4*)(whh + (3 * 64 + j) * 64 + kq * 16);
    float4 A0 = pa[0], A1 = pa[1], A2 = pa[2], A3 = pa[3];
    float4 B0 = pb[0], B1 = pb[1], B2 = pb[2], B3 = pb[3];
    float4 C0 = pc_[0], C1 = pc_[1], C2 = pc_[2], C3 = pc_[3];
    float4 D0 = pd[0], D1 = pd[1], D2 = pd[2], D3 = pd[3];
    const float4* qa = (const float4*)(wih + (0 * 64 + j) * 64 + kq * 16);
    const float4* qb = (const float4*)(wih + (1 * 64 + j) * 64 + kq * 16);
    const float4* qc = (const float4*)(wih + (2 * 64 + j) * 64 + kq * 16);
    const float4* qd = (const float4*)(wih + (3 * 64 + j) * 64 + kq * 16);
    float4 XA0 = qa[0], XA1 = qa[1], XA2 = qa[2], XA3 = qa[3];
    float4 XB0 = qb[0], XB1 = qb[1], XB2 = qb[2], XB3 = qb[3];
    float4 XC0 = qc[0], XC1 = qc[1], XC2 = qc[2], XC3 = qc[3];
    float4 XD0 = qd[0], XD1 = qd[1], XD2 = qd[2], XD3 = qd[3];
    const float bb0 = bih[j] + bhh[j];
    const float bb1 = bih[64 + j] + bhh[64 + j];
    const float bb2 = bih[128 + j] + bhh[128 + j];
    const float bb3 = bih[192 + j] + bhh[192 + j];

    if (tid < 64) s->hbuf[1][(tid >> 4) * 20 + (tid & 15)] = 0.0f;
    float cst = 0.0f;
    __syncthreads();

#define STEP1(k) { \
        const float4* hp_ = (const float4*)&s->hbuf[((k) + 1) & 1][kq * 20]; \
        float4 h0_ = hp_[0], h1_ = hp_[1], h2_ = hp_[2], h3_ = hp_[3]; \
        const float4* xp_ = (const float4*)&s->xst[(k)][kq * 20]; \
        float4 x0_ = xp_[0], x1_ = xp_[1], x2_ = xp_[2], x3_ = xp_[3]; \
        float p0 = dot4(A3, h3_, dot4(A2, h2_, dot4(A1, h1_, dot4(A0, h0_, \
                   dot4(XA3, x3_, dot4(XA2, x2_, dot4(XA1, x1_, dot4(XA0, x0_, 0.f)))))))); \
        float p1 = dot4(B3, h3_, dot4(B2, h2_, dot4(B1, h1_, dot4(B0, h0_, \
                   dot4(XB3, x3_, dot4(XB2, x2_, dot4(XB1, x1_, dot4(XB0, x0_, 0.f)))))))); \
        float p2 = dot4(C3, h3_, dot4(C2, h2_, dot4(C1, h1_, dot4(C0, h0_, \
                   dot4(XC3, x3_, dot4(XC2, x2_, dot4(XC1, x1_, dot4(XC0, x0_, 0.f)))))))); \
        float p3 = dot4(D3, h3_, dot4(D2, h2_, dot4(D1, h1_, dot4(D0, h0_, \
                   dot4(XD3, x3_, dot4(XD2, x2_, dot4(XD1, x1_, dot4(XD0, x0_, 0.f)))))))); \
        p0 += DPPF(p0, 0xB1); p1 += DPPF(p1, 0xB1); p2 += DPPF(p2, 0xB1); p3 += DPPF(p3, 0xB1); \
        p0 += DPPF(p0, 0x4E); p1 += DPPF(p1, 0x4E); p2 += DPPF(p2, 0x4E); p3 += DPPF(p3, 0x4E); \
        float gi = 1.0f - fast_rcp(__expf(p0 + bb0) + 1.0f); \
        float gf = 1.0f - fast_rcp(__expf(p1 + bb1) + 1.0f); \
        float gg = 1.0f - 2.0f * fast_rcp(__expf(2.0f * (p2 + bb2)) + 1.0f); \
        float go = 1.0f - fast_rcp(__expf(p3 + bb3) + 1.0f); \
        cst = fmaf(gf, cst, gi * gg); \
        float h_ = go * tanhfast(cst); \
        if (kq == 0) { s->hbuf[(k) & 1][(j >> 4) * 20 + (j & 15)] = h_; s->ring[(k)][j] = h_; } \
        BAR_LDS(); \
    }

    for (int c = 0; c < 128; ++c) {
        if (tid == 0) {
            while (__hip_atomic_load(&flag1[b * 128 + c], __ATOMIC_RELAXED, SCOPE_AGENT) < 1)
                __builtin_amdgcn_s_sleep(2);
        }
        __syncthreads();
        {
            const ull* src = (const ull*)(h1o + ((long)b * 2048 + c * 16) * 64);
            ull v0 = __hip_atomic_load(src + tid, __ATOMIC_RELAXED, SCOPE_AGENT);
            ull v1 = __hip_atomic_load(src + tid + 256, __ATOMIC_RELAXED, SCOPE_AGENT);
            int u0 = tid, u1 = tid + 256;
            int k0 = u0 >> 5, p0i = (u0 & 31) * 2;
            int k1 = u1 >> 5, p1i = (u1 & 31) * 2;
            *(ull*)&s->xst[k0][(p0i >> 4) * 20 + (p0i & 15)] = v0;
            *(ull*)&s->xst[k1][(p1i >> 4) * 20 + (p1i & 15)] = v1;
        }
        BAR_LDS();
        STEP1(0)  STEP1(1)  STEP1(2)  STEP1(3)
        STEP1(4)  STEP1(5)  STEP1(6)  STEP1(7)
        STEP1(8)  STEP1(9)  STEP1(10) STEP1(11)
        STEP1(12) STEP1(13) STEP1(14) STEP1(15)
        {
            float4* dst = (float4*)(hout + ((long)b * 2048 + c * 16) * 64);
            dst[tid] = ((const float4*)s->ring)[tid];
        }
    }
#undef STEP1
}

// ================= edge body v3: minimal recompute; phase-3 indices compile-time =============
// Window<->full-seq identities: a1w(p)=a1f[t+p-4] for p in [4,45]; a2w(q)=a2f[t+q-7] for q in [7,42].
// Recompute only: conv1 p={0..3,46..49}; conv2 q={0..6,43..49}; conv3 P3={0..8,41..49}.
__device__ __forceinline__ void edge_body(char* smemraw, int b, int t,
    const float* __restrict__ x,
    const float* __restrict__ w1,
    const float* __restrict__ b1, const float* __restrict__ g1,
    const float* __restrict__ be1, const float* __restrict__ m1, const float* __restrict__ vv1,
    const float* __restrict__ b2, const float* __restrict__ g2,
    const float* __restrict__ be2, const float* __restrict__ m2, const float* __restrict__ vv2,
    const float* __restrict__ b3, const float* __restrict__ g3,
    const float* __restrict__ be3, const float* __restrict__ m3, const float* __restrict__ vv3,
    const float* __restrict__ w2t2,
    const float4* __restrict__ w3p4, const float* __restrict__ w3p1,
    const float* __restrict__ a1f, const float* __restrict__ a2f,
    const float* __restrict__ a3f,
    float* __restrict__ feats, int* __restrict__ cnt0)
{
    EdgeS* s = (EdgeS*)smemraw;
    const int tid = threadIdx.x;

    // ---- phase 0: zero pads, bn consts, x slices, interior fills, a3f staging ----
    for (int idx = tid; idx < 1088; idx += 256) {
        if (idx < 768) {   // A1 zero slots {0,1,2,13,14,15,26..31}
            int row = idx / 12, z = idx - row * 12;
            int slot = (z < 3) ? z : (z < 6 ? 10 + z : 20 + z);
            s->A1[row * 36 + slot] = 0.0f;
        } else {           // A2 zero slots {0,1,13,14,15,27..31}
            int e = idx - 768;
            int row = e / 10, z = e - row * 10;
            int slot = (z < 2) ? z : (z < 5 ? 11 + z : 22 + z);
            s->A2[row * 36 + slot] = 0.0f;
        }
    }
    if (tid < 128) {       // interior a3f staging (v3 = t .. t+31)
        int dv = tid >> 2, o4 = (tid & 3) * 4;
        *(float4*)&s->pi[dv * 16 + o4] =
            *(const float4*)&a3f[((long)b * 2080 + t + dv) * 16 + o4];
    }
    if (tid < 64) {
        float sc = g1[tid] * rsqrtf(vv1[tid] + EPSV);
        s->s1[tid] = sc;
        s->t1[tid] = (b1[tid] - m1[tid]) * sc + be1[tid];
    } else if (tid < 96) {
        int o = tid - 64;
        float sc = g2[o] * rsqrtf(vv2[o] + EPSV);
        s->s2[o] = sc;
        s->t2[o] = (b2[o] - m2[o]) * sc + be2[o];
    } else if (tid < 112) {
        int o = tid - 96;
        float sc = g3[o] * rsqrtf(vv3[o] + EPSV);
        s->s3[o] = sc;
        s->t3[o] = (b3[o] - m3[o]) * sc + be3[o];
    } else if (tid < 128) {
        int m = tid - 112;           // xl[m] = win[m-4]: 0 for m<4, else x[t-53+m]
        float v = 0.0f;
        if (m >= 4) { int gi = t - 53 + m; if (gi >= 0) v = x[b * 2048 + gi]; }
        s->xl[m] = v;
    } else if (tid < 144) {
        int m = tid - 128;           // xr[m] = win[42+m]: 0 for m>7, else x[t-7+m]
        float v = 0.0f;
        if (m <= 7) { int gi = t - 7 + m; if (gi >= 0) v = x[b * 2048 + gi]; }
        s->xr[m] = v;
    }
    {   // interior fills: one float4 global load per thread, 4 scalar LDS writes
        if (tid < 96) {              // A1 left f: slots 7+d = a1f[t+d], d=0..5
            int d = tid >> 4, i4 = (tid & 15) * 4;
            float4 f = *(const float4*)&a1f[((long)b * 2089 + t + d) * 64 + i4];
            int slot = 7 + d;
            s->A1[(i4 + 0) * 36 + slot] = f.x;
            s->A1[(i4 + 1) * 36 + slot] = f.y;
            s->A1[(i4 + 2) * 36 + slot] = f.z;
            s->A1[(i4 + 3) * 36 + slot] = f.w;
        } else if (tid < 192) {      // A1 right f: slots 16+d = a1f[t+36+d], d=0..5
            int e = tid - 96;
            int d = e >> 4, i4 = (e & 15) * 4;
            float4 f = *(const float4*)&a1f[((long)b * 2089 + t + 36 + d) * 64 + i4];
            int slot = 16 + d;
            s->A1[(i4 + 0) * 36 + slot] = f.x;
            s->A1[(i4 + 1) * 36 + slot] = f.y;
            s->A1[(i4 + 2) * 36 + slot] = f.z;
            s->A1[(i4 + 3) * 36 + slot] = f.w;
        } else if (tid < 224) {      // A2 left f: slots 9+d = a2f[t+d], d=0..3
            int e = tid - 192;
            int d = e >> 3, i4 = (e & 7) * 4;
            float4 f = *(const float4*)&a2f[((long)b * 2083 + t + d) * 32 + i4];
            int slot = 9 + d;
            s->A2[(i4 + 0) * 36 + slot] = f.x;
            s->A2[(i4 + 1) * 36 + slot] = f.y;
            s->A2[(i4 + 2) * 36 + slot] = f.z;
            s->A2[(i4 + 3) * 36 + slot] = f.w;
        } else {                     // A2 right f: slots 16+d = a2f[t+32+d], d=0..3
            int e = tid - 224;
            int d = e >> 3, i4 = (e & 7) * 4;
            float4 f = *(const float4*)&a2f[((long)b * 2083 + t + 32 + d) * 32 + i4];
            int slot = 16 + d;
            s->A2[(i4 + 0) * 36 + slot] = f.x;
            s->A2[(i4 + 1) * 36 + slot] = f.y;
            s->A2[(i4 + 2) * 36 + slot] = f.z;
            s->A2[(i4 + 3) * 36 + slot] = f.w;
        }
    }
    __syncthreads();

    {   // ---- phase 1: conv1 edges, 8 positions: left p=g -> slot 3+g, right p=46+g -> slot 22+g
        const int o = tid >> 2, g = tid & 3;
        float wv[9];
        #pragma unroll
        for (int k = 0; k < 9; ++k) wv[k] = w1[o * 9 + k];
        float accL = 0.0f, accR = 0.0f;
        #pragma unroll
        for (int k = 0; k < 9; ++k) {
            accL = fmaf(wv[k], s->xl[g + k], accL);
            accR = fmaf(wv[k], s->xr[g + k], accR);
        }
        float sc = s->s1[o], tc = s->t1[o];
        s->A1[o * 36 + 3 + g]  = fmaxf(accL * sc + tc, 0.0f);
        s->A1[o * 36 + 22 + g] = fmaxf(accR * sc + tc, 0.0f);
    }
    __syncthreads();

    {   // ---- phase 2: conv2 edges, 7 q per side; 4-way i-split + DPP reduce
        const int o = tid >> 3, side = (tid >> 2) & 1, isub = tid & 3;
        const int sbase = side * 16;
        float acc[7];
        #pragma unroll
        for (int q = 0; q < 7; ++q) acc[q] = 0.0f;
        #pragma unroll 2
        for (int ii = 0; ii < 16; ++ii) {
            int i = 4 * ii + isub;
            const float* rp = &s->A1[i * 36 + sbase];
            float4 R0 = *(const float4*)&rp[0];
            float4 R1 = *(const float4*)&rp[4];
            float4 R2 = *(const float4*)&rp[8];
            float r12 = rp[12];
            float av[13] = {R0.x, R0.y, R0.z, R0.w, R1.x, R1.y, R1.z, R1.w,
                            R2.x, R2.y, R2.z, R2.w, r12};
            const float4* wp = (const float4*)&w2t2[(i * 32 + o) * 8];
            float4 Wa = wp[0], Wb = wp[1];
            float wk[7] = {Wa.x, Wa.y, Wa.z, Wa.w, Wb.x, Wb.y, Wb.z};
            #pragma unroll
            for (int k = 0; k < 7; ++k) {
                #pragma unroll
                for (int q = 0; q < 7; ++q) acc[q] = fmaf(wk[k], av[q + k], acc[q]);
            }
        }
        #pragma unroll
        for (int q = 0; q < 7; ++q) {
            acc[q] += DPPF(acc[q], 0xB1);
            acc[q] += DPPF(acc[q], 0x4E);
        }
        if (isub == 0) {
            float sc = s->s2[o], tc = s->t2[o];
            #pragma unroll
            for (int q = 0; q < 7; ++q) {
                float r = fmaxf(acc[q] * sc + tc, 0.0f);
                s->A2[o * 36 + (side ? 20 + q : 2 + q)] = r;
            }
        }
    }
    __syncthreads();

    {   // ---- phase 3: conv3 edges; wave-uniform pg/side branches, ALL tap indices compile-time
        const int o = (tid >> 2) & 15, isub = tid & 3;
        const int side = (tid >> 6) & 1, pg = tid >> 7;   // wave-uniform (64-lane granularity)
        float acc[5];
        #pragma unroll
        for (int n = 0; n < 5; ++n) acc[n] = 0.0f;
        if (pg == 0) {          // positions P=0..4, taps 0..8
            #pragma unroll 2
            for (int ii = 0; ii < 8; ++ii) {
                int i = 4 * ii + isub;
                const float* rp = &s->A2[i * 36 + side * 16];
                float4 R0 = *(const float4*)&rp[0];
                float4 R1 = *(const float4*)&rp[4];
                float t8 = rp[8];
                float av[9] = {R0.x, R0.y, R0.z, R0.w, R1.x, R1.y, R1.z, R1.w, t8};
                float4 wa = w3p4[i * 16 + o];
                float w4 = w3p1[i * 16 + o];
                #pragma unroll
                for (int n = 0; n < 5; ++n) {
                    acc[n] = fmaf(wa.x, av[n], acc[n]);
                    acc[n] = fmaf(wa.y, av[n + 1], acc[n]);
                    acc[n] = fmaf(wa.z, av[n + 2], acc[n]);
                    acc[n] = fmaf(wa.w, av[n + 3], acc[n]);
                    acc[n] = fmaf(w4,   av[n + 4], acc[n]);
                }
            }
        } else {                // positions P=5..8, taps 5..12
            #pragma unroll 2
            for (int ii = 0; ii < 8; ++ii) {
                int i = 4 * ii + isub;
                const float* rp = &s->A2[i * 36 + side * 16];
                float4 R1 = *(const float4*)&rp[4];
                float4 R2 = *(const float4*)&rp[8];
                float t12 = rp[12];
                float av[8] = {R1.y, R1.z, R1.w, R2.x, R2.y, R2.z, R2.w, t12}; // taps 5..12
                float4 wa = w3p4[i * 16 + o];
                float w4 = w3p1[i * 16 + o];
                #pragma unroll
                for (int n = 0; n < 4; ++n) {
                    acc[n] = fmaf(wa.x, av[n], acc[n]);
                    acc[n] = fmaf(wa.y, av[n + 1], acc[n]);
                    acc[n] = fmaf(wa.z, av[n + 2], acc[n]);
                    acc[n] = fmaf(wa.w, av[n + 3], acc[n]);
                    acc[n] = fmaf(w4,   av[n + 4], acc[n]);
                }
            }
        }
        #pragma unroll
        for (int n = 0; n < 5; ++n) {
            acc[n] += DPPF(acc[n], 0xB1);
            acc[n] += DPPF(acc[n], 0x4E);
        }
        if (isub == 0) {
            float sc = s->s3[o], tc = s->t3[o];
            if (pg == 0) {
                #pragma unroll
                for (int n = 0; n < 5; ++n)
                    s->psumE[(side * 9 + n) * 16 + o] = fmaxf(acc[n] * sc + tc, 0.0f);
            } else {
                #pragma unroll
                for (int n = 0; n < 4; ++n)
                    s->psumE[(side * 9 + 5 + n) * 16 + o] = fmaxf(acc[n] * sc + tc, 0.0f);
            }
        }
    }
    __syncthreads();

    if (tid < 16) {
        float e = 0.0f;
        #pragma unroll
        for (int P3 = 0; P3 < 18; ++P3) e += s->psumE[P3 * 16 + tid];
        float ii = 0.0f;
        #pragma unroll
        for (int dv = 0; dv < 32; ++dv) ii += s->pi[dv * 16 + tid];
        __hip_atomic_store(&feats[((long)b * 2048 + t) * 16 + tid], (e + ii) * (1.0f / 50.0f),
                           __ATOMIC_RELAXED, SCOPE_AGENT);
    }
    __syncthreads();   // drains vmcnt(0): feats stores complete before counter bump
    if (tid == 0)
        __hip_atomic_fetch_add(&cnt0[b * 128 + (t >> 4)], 1, __ATOMIC_RELAXED, SCOPE_AGENT);
}

// ================= fused: blocks 0-15 lstm0, 16-31 lstm1, 32+ edge (t-major) =================
__global__ __launch_bounds__(256, 2) void fused_kernel(
    const float* __restrict__ x,
    const float* __restrict__ w1, const float* __restrict__ b1,
    const float* __restrict__ g1, const float* __restrict__ be1,
    const float* __restrict__ m1, const float* __restrict__ vv1,
    const float* __restrict__ b2,
    const float* __restrict__ g2, const float* __restrict__ be2,
    const float* __restrict__ m2, const float* __restrict__ vv2,
    const float* __restrict__ b3,
    const float* __restrict__ g3, const float* __restrict__ be3,
    const float* __restrict__ m3, const float* __restrict__ vv3,
    const float* __restrict__ w2t2,
    const float4* __restrict__ w3p4, const float* __restrict__ w3p1,
    const float* __restrict__ a1f, const float* __restrict__ a2f,
    const float* __restrict__ a3f,
    const float* __restrict__ wih0, const float* __restrict__ whh0,
    const float* __restrict__ bih0, const float* __restrict__ bhh0,
    const float* __restrict__ wih1, const float* __restrict__ whh1,
    const float* __restrict__ bih1, const float* __restrict__ bhh1,
    float* __restrict__ feats, float* __restrict__ h1o, float* __restrict__ h2o,
    int* __restrict__ cnt0, int* __restrict__ flag1)
{
    __shared__ __align__(16) char smem[sizeof(EdgeS) > sizeof(RecS) ? sizeof(EdgeS) : sizeof(RecS)];

    if (blockIdx.x < 16) { rec0_body(smem, blockIdx.x, feats, wih0, whh0, bih0, bhh0, h1o, cnt0, flag1); return; }
    if (blockIdx.x < 32) { rec1_body(smem, blockIdx.x - 16, h1o, wih1, whh1, bih1, bhh1, h2o, flag1); return; }

    int w = blockIdx.x - 32;
    int b = w & 15;          // t-major: early t for all batches first
    int t = w >> 4;
    edge_body(smem, b, t, x, w1, b1, g1, be1, m1, vv1, b2, g2, be2, m2, vv2,
              b3, g3, be3, m3, vv3, w2t2, w3p4, w3p1, a1f, a2f, a3f, feats, cnt0);
}

// ---------------- FC head ----------------
__global__ __launch_bounds__(256) void fc_kernel(
    const float* __restrict__ h2o,
    const float* __restrict__ fc1w, const float* __restrict__ fc1b,
    const float* __restrict__ fc2w, const float* __restrict__ fc2b,
    float* __restrict__ out)
{
    int r = blockIdx.x * 256 + threadIdx.x;
    float h[64];
    const float4* hp = (const float4*)(h2o + (long)r * 64);
    #pragma unroll
    for (int i = 0; i < 16; ++i) {
        float4 v = hp[i];
        h[4 * i] = v.x; h[4 * i + 1] = v.y; h[4 * i + 2] = v.z; h[4 * i + 3] = v.w;
    }
    float l0 = fc2b[0], l1 = fc2b[1];
    #pragma unroll 4
    for (int j = 0; j < 32; ++j) {
        float z = fc1b[j];
        #pragma unroll
        for (int k = 0; k < 64; ++k) z = fmaf(h[k], fc1w[j * 64 + k], z);
        z = fmaxf(z, 0.0f);
        l0 = fmaf(z, fc2w[j], l0);
        l1 = fmaf(z, fc2w[32 + j], l1);
    }
    out[r * 2] = l0;
    out[r * 2 + 1] = l1;
}

extern "C" void kernel_launch(void* const* d_in, const int* in_sizes, int n_in,
                              void* d_out, int out_size, void* d_ws, size_t ws_size,
                              hipStream_t stream) {
    const float* x    = (const float*)d_in[0];
    const float* w1   = (const float*)d_in[1];
    const float* b1   = (const float*)d_in[2];
    const float* g1   = (const float*)d_in[3];
    const float* be1  = (const float*)d_in[4];
    const float* m1   = (const float*)d_in[5];
    const float* v1   = (const float*)d_in[6];
    const float* w2   = (const float*)d_in[7];
    const float* b2   = (const float*)d_in[8];
    const float* g2   = (const float*)d_in[9];
    const float* be2  = (const float*)d_in[10];
    const float* m2   = (const float*)d_in[11];
    const float* v2   = (const float*)d_in[12];
    const float* w3   = (const float*)d_in[13];
    const float* b3   = (const float*)d_in[14];
    const float* g3   = (const float*)d_in[15];
    const float* be3  = (const float*)d_in[16];
    const float* m3   = (const float*)d_in[17];
    const float* v3   = (const float*)d_in[18];
    const float* wih0 = (const float*)d_in[19];
    const float* whh0 = (const float*)d_in[20];
    const float* bih0 = (const float*)d_in[21];
    const float* bhh0 = (const float*)d_in[22];
    const float* wih1 = (const float*)d_in[23];
    const float* whh1 = (const float*)d_in[24];
    const float* bih1 = (const float*)d_in[25];
    const float* bhh1 = (const float*)d_in[26];
    const float* fc1w = (const float*)d_in[27];
    const float* fc1b = (const float*)d_in[28];
    const float* fc2w = (const float*)d_in[29];
    const float* fc2b = (const float*)d_in[30];
    float* out = (float*)d_out;

    float* ws    = (float*)d_ws;
    float* feats = ws;                            // 524288
    float* h2o   = feats + 32768 * 16;            // 2097152
    float* w2t2  = h2o + 32768 * 64;              // 16384
    float* w3p4f = w2t2 + 16384;                  // 2048
    float* w3p1  = w3p4f + 2048;                  // 512
    float* h1o   = w3p1 + 512;                    // 2097152
    float* a1f   = h1o + 32768 * 64;              // 16*2089*64 = 2139136
    float* a2f   = a1f + 16 * 2089 * 64;          // 16*2083*32 = 1066496
    float* a3f   = a2f + 16 * 2083 * 32;          // 16*2080*16 = 532480
    int*   cnt0  = (int*)(a3f + 16 * 2080 * 16);  // 2048
    int*   flag1 = cnt0 + 2048;                   // 2048

    hipLaunchKernelGGL(pack_kernel, dim3(82), dim3(256), 0, stream,
                       w2, w3, w2t2, (float4*)w3p4f, w3p1, cnt0);
    hipLaunchKernelGGL(conv1f_kernel, dim3(33, 16), dim3(256), 0, stream,
                       x, w1, b1, g1, be1, m1, v1, a1f);
    hipLaunchKernelGGL(conv2f_kernel, dim3(33, 16), dim3(256), 0, stream,
                       a1f, w2t2, b2, g2, be2, m2, v2, a2f);
    hipLaunchKernelGGL(conv3f_kernel, dim3(17, 16), dim3(256), 0, stream,
                       a2f, (const float4*)w3p4f, w3p1, b3, g3, be3, m3, v3, a3f);
    hipLaunchKernelGGL(fused_kernel, dim3(32 + 32768), dim3(256), 0, stream,
                       x, w1, b1, g1, be1, m1, v1, b2, g2, be2, m2, v2,
                       b3, g3, be3, m3, v3, w2t2, (const float4*)w3p4f, w3p1,
                       a1f, a2f, a3f,
                       wih0, whh0, bih0, bhh0, wih1, whh1, bih1, bhh1,
                       feats, h1o, h2o, cnt0, flag1);
    hipLaunchKernelGGL(fc_kernel, dim3(128), dim3(256), 0, stream,
                       h2o, fc1w, fc1b, fc2w, fc2b, out);
}